// Round 11
// baseline (337.874 us; speedup 1.0000x reference)
//
#include <hip/hip_runtime.h>
#include <hip/hip_bf16.h>

#define B_ 128
#define I_ 2048
#define O_ 2048
#define SEG 10
#define BK 64
#define NST (I_ / BK)      // 32 k-steps
#define XTILE 16384        // x tile: 128 rows x 64 k x 2B bf16, swizzled
#define DCH 2560           // D chunk: 64 i x 10 j x 4B f32, contiguous in D
#define DLS 2816           // + 256 B w chunk

typedef __attribute__((ext_vector_type(8))) short bf16x8;
typedef __attribute__((ext_vector_type(4))) float f32x4;

static __device__ __forceinline__ unsigned short f2bf(float f) {
    unsigned u = __float_as_uint(f);
    u += 0x7FFFu + ((u >> 16) & 1u);
    return (unsigned short)(u >> 16);
}

static __device__ __forceinline__ unsigned cvt2(float lo, float hi) {
    __hip_bfloat162 h = __float22bfloat162_rn(make_float2(lo, hi));
    return *reinterpret_cast<unsigned*>(&h);
}

#define GLDS16(SRC, DST) \
    __builtin_amdgcn_global_load_lds( \
        (const __attribute__((address_space(1))) unsigned*)(SRC), \
        (__attribute__((address_space(3))) unsigned*)(DST), 16, 0, 0)
#define GLDS4(SRC, DST) \
    __builtin_amdgcn_global_load_lds( \
        (const __attribute__((address_space(1))) unsigned*)(SRC), \
        (__attribute__((address_space(3))) unsigned*)(DST), 4, 0, 0)

// ---------------------------------------------------------------------------
// Prepass: x f32 -> xb bf16, 32 tiles of [128 rows][64 k], XOR-swizzled
// ---------------------------------------------------------------------------
__global__ void xconv(const float* __restrict__ x, char* __restrict__ xb) {
    int idx = blockIdx.x * 256 + threadIdx.x;
    int row = idx >> 8;
    int c   = idx & 255;
    int k0  = c * 8;
    int tt  = k0 >> 6;
    int kl  = k0 & 63;

    const float* xp = x + (size_t)row * I_ + k0;
    float4 a = *reinterpret_cast<const float4*>(xp);
    float4 b = *reinterpret_cast<const float4*>(xp + 4);

    bf16x8 h;
    h[0] = (short)f2bf(a.x); h[1] = (short)f2bf(a.y);
    h[2] = (short)f2bf(a.z); h[3] = (short)f2bf(a.w);
    h[4] = (short)f2bf(b.x); h[5] = (short)f2bf(b.y);
    h[6] = (short)f2bf(b.z); h[7] = (short)f2bf(b.w);

    size_t off = (size_t)tt * XTILE + row * 128 + ((kl * 2) ^ ((row & 7) << 4));
    *reinterpret_cast<bf16x8*>(xb + off) = h;
}

// ---------------------------------------------------------------------------
// Main fused kernel == R10, run REPEATED x4 (acc reset per rep, identical
// output, 4x duration) so it clears the top-5 profiler cutoff with counters.
// ---------------------------------------------------------------------------
__global__ __launch_bounds__(256, 2) void neuro_fused(
    const char*  __restrict__ xb,
    const float* __restrict__ ctx,
    const float* __restrict__ w,
    const float* __restrict__ bias,
    const float* __restrict__ astro,
    const float* __restrict__ D,
    float* __restrict__ out)
{
    __shared__ __align__(16) char xs[2][XTILE];
    __shared__ __align__(16) char dls[4][2][DLS];

    const int tid  = threadIdx.x;
    const int wave = tid >> 6;
    const int lane = tid & 63;
    const int o    = blockIdx.x * 4 + wave;
    const int col  = lane & 15;
    const int g    = lane >> 4;

    float am = astro[o] * ctx[o];
    am = 1.0f / (1.0f + __expf(-am));
    const float bo = bias[o];

    const int fbase = (col < 10) ? col * 4 : DCH;
    const int fstr  = (col < 10) ? 40 : 4;
    const int sw    = (col & 7) << 4;

    auto stage_x = [&](int t, int buf) {
        const char* src = xb + (size_t)t * XTILE + wave * 4096 + lane * 16;
        char* dst = &xs[buf][wave * 4096];
#pragma unroll
        for (int c = 0; c < 4; ++c)
            GLDS16(src + c * 1024, dst + c * 1024);
    };

    auto stage_d = [&](int t, int buf) {
        const char* srcD = (const char*)D + (size_t)o * (I_ * SEG * 4) + (size_t)t * DCH;
        char* dst = &dls[wave][buf][0];
#pragma unroll
        for (int c = 0; c < 2; ++c)
            GLDS16(srcD + c * 1024 + lane * 16, dst + c * 1024);
#pragma unroll
        for (int c = 0; c < 2; ++c)
            GLDS4(srcD + 2048 + c * 256 + lane * 4, dst + 2048 + c * 256);
        const char* srcW = (const char*)w + (size_t)o * (I_ * 4) + t * (BK * 4);
        GLDS4(srcW + lane * 4, dst + DCH);
    };

    f32x4 acc[8];

    auto compute = [&](int buf) {
        const char* xbase = &xs[buf][0];
        const char* dbase = &dls[wave][buf][0];
        bf16x8 af[2][8];
#pragma unroll
        for (int kk = 0; kk < 2; ++kk) {
            const int kswz = (64 * kk + 16 * g) ^ sw;
#pragma unroll
            for (int m = 0; m < 8; ++m)
                af[kk][m] = *reinterpret_cast<const bf16x8*>(
                    xbase + (m * 16 + col) * 128 + kswz);
        }
        float bv[2][8];
#pragma unroll
        for (int kk = 0; kk < 2; ++kk) {
            const char* fp = dbase + fbase + (32 * kk + 8 * g) * fstr;
#pragma unroll
            for (int e = 0; e < 8; ++e)
                bv[kk][e] = *reinterpret_cast<const float*>(fp + e * fstr);
        }
#pragma unroll
        for (int kk = 0; kk < 2; ++kk) {
            union { bf16x8 v; unsigned u[4]; } bf;
#pragma unroll
            for (int e2 = 0; e2 < 4; ++e2)
                bf.u[e2] = cvt2(bv[kk][2 * e2], bv[kk][2 * e2 + 1]);
#pragma unroll
            for (int m = 0; m < 8; ++m)
                acc[m] = __builtin_amdgcn_mfma_f32_16x16x32_bf16(af[kk][m], bf.v, acc[m], 0, 0, 0);
        }
    };

#pragma unroll 1
    for (int rep = 0; rep < 4; ++rep) {
#pragma unroll
        for (int m = 0; m < 8; ++m) acc[m] = (f32x4){0.f, 0.f, 0.f, 0.f};

        stage_x(0, 0);
        stage_d(0, 0);
        __syncthreads();

#pragma unroll 1
        for (int t = 0; t < NST; t += 2) {
            stage_x(t + 1, 1);
            stage_d(t + 1, 1);
            compute(0);
            __syncthreads();

            if (t + 2 < NST) {
                stage_x(t + 2, 0);
                stage_d(t + 2, 0);
            }
            compute(1);
            __syncthreads();
        }
    }

#pragma unroll
    for (int m = 0; m < 8; ++m) {
#pragma unroll
        for (int r = 0; r < 4; ++r) {
            float v = acc[m][r];
            float dend = (col < 10) ? fmaxf(v, 0.0f) : 0.0f;
#pragma unroll
            for (int s = 1; s < 16; s <<= 1)
                dend += __shfl_xor(dend, s, 64);
            float lin = __shfl(v, (lane & 48) | 10, 64);
            if (col == 0) {
                int b = m * 16 + g * 4 + r;
                out[(size_t)b * O_ + o] = dend + am * lin + bo;
            }
        }
    }
}

// ---------------------------------------------------------------------------
// PROBE 1: staging skeleton only (GLDS + barriers, x6). No LDS reads, no MFMA.
// ---------------------------------------------------------------------------
__global__ __launch_bounds__(256, 2) void probe_stage(
    const char*  __restrict__ xb,
    const float* __restrict__ w,
    const float* __restrict__ D,
    float* __restrict__ sink)
{
    __shared__ __align__(16) char xs[2][XTILE];
    __shared__ __align__(16) char dls[4][2][DLS];

    const int tid  = threadIdx.x;
    const int wave = tid >> 6;
    const int lane = tid & 63;
    const int o    = blockIdx.x * 4 + wave;

    auto stage_x = [&](int t, int buf) {
        const char* src = xb + (size_t)t * XTILE + wave * 4096 + lane * 16;
        char* dst = &xs[buf][wave * 4096];
#pragma unroll
        for (int c = 0; c < 4; ++c)
            GLDS16(src + c * 1024, dst + c * 1024);
    };

    auto stage_d = [&](int t, int buf) {
        const char* srcD = (const char*)D + (size_t)o * (I_ * SEG * 4) + (size_t)t * DCH;
        char* dst = &dls[wave][buf][0];
#pragma unroll
        for (int c = 0; c < 2; ++c)
            GLDS16(srcD + c * 1024 + lane * 16, dst + c * 1024);
#pragma unroll
        for (int c = 0; c < 2; ++c)
            GLDS4(srcD + 2048 + c * 256 + lane * 4, dst + 2048 + c * 256);
        const char* srcW = (const char*)w + (size_t)o * (I_ * 4) + t * (BK * 4);
        GLDS4(srcW + lane * 4, dst + DCH);
    };

#pragma unroll 1
    for (int rep = 0; rep < 6; ++rep) {
        stage_x(0, 0);
        stage_d(0, 0);
        __syncthreads();
#pragma unroll 1
        for (int t = 0; t < NST; t += 2) {
            stage_x(t + 1, 1);
            stage_d(t + 1, 1);
            __syncthreads();
            if (t + 2 < NST) {
                stage_x(t + 2, 0);
                stage_d(t + 2, 0);
            }
            __syncthreads();
        }
    }
    // keep LDS observable
    sink[(size_t)blockIdx.x * 256 + tid] =
        *reinterpret_cast<float*>(&xs[0][(tid & 1023) * 4]);
}

// ---------------------------------------------------------------------------
// PROBE 2: compute skeleton only (LDS reads + cvt + MFMA + epilogue, x4).
// No VMEM staging, one barrier per rep (defeats cross-rep LDS CSE).
// ---------------------------------------------------------------------------
__global__ __launch_bounds__(256, 2) void probe_comp(
    const float* __restrict__ ctx,
    const float* __restrict__ bias,
    const float* __restrict__ astro,
    float* __restrict__ sink)
{
    __shared__ __align__(16) char xs[2][XTILE];
    __shared__ __align__(16) char dls[4][2][DLS];

    const int tid  = threadIdx.x;
    const int wave = tid >> 6;
    const int lane = tid & 63;
    const int o    = blockIdx.x * 4 + wave;
    const int col  = lane & 15;
    const int g    = lane >> 4;

    float am = astro[o] * ctx[o];
    am = 1.0f / (1.0f + __expf(-am));
    const float bo = bias[o];

    const int fbase = (col < 10) ? col * 4 : DCH;
    const int fstr  = (col < 10) ? 40 : 4;
    const int sw    = (col & 7) << 4;

    f32x4 acc[8];
#pragma unroll
    for (int m = 0; m < 8; ++m) acc[m] = (f32x4){0.f, 0.f, 0.f, 0.f};

    auto compute = [&](int buf) {
        const char* xbase = &xs[buf][0];
        const char* dbase = &dls[wave][buf][0];
        bf16x8 af[2][8];
#pragma unroll
        for (int kk = 0; kk < 2; ++kk) {
            const int kswz = (64 * kk + 16 * g) ^ sw;
#pragma unroll
            for (int m = 0; m < 8; ++m)
                af[kk][m] = *reinterpret_cast<const bf16x8*>(
                    xbase + (m * 16 + col) * 128 + kswz);
        }
        float bv[2][8];
#pragma unroll
        for (int kk = 0; kk < 2; ++kk) {
            const char* fp = dbase + fbase + (32 * kk + 8 * g) * fstr;
#pragma unroll
            for (int e = 0; e < 8; ++e)
                bv[kk][e] = *reinterpret_cast<const float*>(fp + e * fstr);
        }
#pragma unroll
        for (int kk = 0; kk < 2; ++kk) {
            union { bf16x8 v; unsigned u[4]; } bf;
#pragma unroll
            for (int e2 = 0; e2 < 4; ++e2)
                bf.u[e2] = cvt2(bv[kk][2 * e2], bv[kk][2 * e2 + 1]);
#pragma unroll
            for (int m = 0; m < 8; ++m)
                acc[m] = __builtin_amdgcn_mfma_f32_16x16x32_bf16(af[kk][m], bf.v, acc[m], 0, 0, 0);
        }
    };

#pragma unroll 1
    for (int rep = 0; rep < 4; ++rep) {
        __syncthreads();
#pragma unroll 1
        for (int t = 0; t < NST; t += 2) {
            compute(0);
            compute(1);
        }
    }

#pragma unroll
    for (int m = 0; m < 8; ++m) {
#pragma unroll
        for (int r = 0; r < 4; ++r) {
            float v = acc[m][r];
            float dend = (col < 10) ? fmaxf(v, 0.0f) : 0.0f;
#pragma unroll
            for (int s = 1; s < 16; s <<= 1)
                dend += __shfl_xor(dend, s, 64);
            float lin = __shfl(v, (lane & 48) | 10, 64);
            if (col == 0) {
                int b = m * 16 + g * 4 + r;
                sink[(size_t)b * O_ + o] = dend + am * lin + bo;
            }
        }
    }
}

extern "C" void kernel_launch(void* const* d_in, const int* in_sizes, int n_in,
                              void* d_out, int out_size, void* d_ws, size_t ws_size,
                              hipStream_t stream) {
    const float* x     = (const float*)d_in[0];
    const float* ctx   = (const float*)d_in[1];
    // d_in[2] = prev_activation (unused by the reference output)
    const float* w     = (const float*)d_in[3];
    const float* bias  = (const float*)d_in[4];
    const float* astro = (const float*)d_in[5];
    const float* D     = (const float*)d_in[6];
    float* out = (float*)d_out;

    char*  xb    = (char*)d_ws;                       // 512 KiB bf16 x tiles
    float* sink1 = (float*)((char*)d_ws + (1 << 20)); // probe sinks
    float* sink2 = (float*)((char*)d_ws + (2 << 20));

    xconv<<<dim3(128), dim3(256), 0, stream>>>(x, xb);
    neuro_fused<<<dim3(512), dim3(256), 0, stream>>>(xb, ctx, w, bias, astro, D, out);
    probe_stage<<<dim3(512), dim3(256), 0, stream>>>(xb, w, D, sink1);
    probe_comp<<<dim3(512), dim3(256), 0, stream>>>(ctx, bias, astro, sink2);
}

// Round 12
// 48.863 us; speedup vs baseline: 6.9147x; 6.9147x over previous
//
#include <hip/hip_runtime.h>
#include <hip/hip_bf16.h>

#define B_ 128
#define I_ 2048
#define O_ 2048
#define SEG 10
#define BK 32
#define NST (I_ / BK)      // 64 k-steps
#define XTILE 8192         // x tile: 128 rows x 32 k x 2B bf16, swizzled
#define DCH 1280           // D chunk: 32 i x 10 j x 4B f32 (contiguous)
#define DLS 1408           // + 128 B w chunk

typedef __attribute__((ext_vector_type(8))) short bf16x8;
typedef __attribute__((ext_vector_type(4))) float f32x4;

static __device__ __forceinline__ unsigned short f2bf(float f) {
    unsigned u = __float_as_uint(f);
    u += 0x7FFFu + ((u >> 16) & 1u);
    return (unsigned short)(u >> 16);
}

static __device__ __forceinline__ unsigned cvt2(float lo, float hi) {
    __hip_bfloat162 h = __float22bfloat162_rn(make_float2(lo, hi));
    return *reinterpret_cast<unsigned*>(&h);
}

#define GLDS16(SRC, DST) \
    __builtin_amdgcn_global_load_lds( \
        (const __attribute__((address_space(1))) unsigned*)(SRC), \
        (__attribute__((address_space(3))) unsigned*)(DST), 16, 0, 0)
#define GLDS4(SRC, DST) \
    __builtin_amdgcn_global_load_lds( \
        (const __attribute__((address_space(1))) unsigned*)(SRC), \
        (__attribute__((address_space(3))) unsigned*)(DST), 4, 0, 0)

#define WAITVM(N) asm volatile("s_waitcnt vmcnt(" #N ")" ::: "memory")
#define BARRIER() do { __builtin_amdgcn_sched_barrier(0); \
                       __builtin_amdgcn_s_barrier(); \
                       __builtin_amdgcn_sched_barrier(0); } while (0)

// ---------------------------------------------------------------------------
// Prepass: x [128][2048] f32 -> xb: 64 tiles of [128 rows][32 k] bf16.
// Row stride 64 B; XOR swizzle: byte(row,kl) = row*64 + ((kl*2) ^ sw2(row)),
// sw2(row) = ((row>>1)&3)<<4   (verified in R4/R5).
// ---------------------------------------------------------------------------
__global__ void xconv(const float* __restrict__ x, char* __restrict__ xb) {
    int idx = blockIdx.x * 256 + threadIdx.x;   // one 8-k chunk each
    int row = idx >> 8;
    int c   = idx & 255;
    int k0  = c * 8;
    int tt  = k0 >> 5;                          // tile 0..63
    int kl  = k0 & 31;

    const float* xp = x + (size_t)row * I_ + k0;
    float4 a = *reinterpret_cast<const float4*>(xp);
    float4 b = *reinterpret_cast<const float4*>(xp + 4);

    bf16x8 h;
    h[0] = (short)f2bf(a.x); h[1] = (short)f2bf(a.y);
    h[2] = (short)f2bf(a.z); h[3] = (short)f2bf(a.w);
    h[4] = (short)f2bf(b.x); h[5] = (short)f2bf(b.y);
    h[6] = (short)f2bf(b.z); h[7] = (short)f2bf(b.w);

    int sw = ((row >> 1) & 3) << 4;
    size_t off = (size_t)tt * XTILE + row * 64 + ((kl * 2) ^ sw);
    *reinterpret_cast<bf16x8*>(xb + off) = h;
}

// ---------------------------------------------------------------------------
// Main kernel: PRODUCER/CONSUMER wave specialization.
// Grid 512 x 256 thr (4 waves), 2 blocks/CU. Block owns 4 o's, full K.
//   waves 0,1 = producers: DMA only. Producer p stages x-half p (4 GLDS16)
//     and D+w for o_local 2p,2p+1 (6 ops) each step = 10 vmcnt ops/step.
//     4-deep buffers, 3 tiles in flight, counted WAITVM(20) (never 0 until
//     tail) -> consumers never see DMA latency.
//   waves 2,3 = consumers: zero VMEM in loop. Consumer c computes o_local
//     2c,2c+1: 8 shared A-frags (b128, swizzled 2-way), 16 B b32 reads,
//     8 cvt_pk, 16 MFMA per step.
// ONE barrier per step. Invariant: in iter u, producer's WAITVM from iter
// u-1 guarantees tile u landed before iter u's barrier; issue(u+3) happens
// after the barrier that ends all reads of slot (u+3)%4 (= iter u-1's).
// ---------------------------------------------------------------------------
__global__ __launch_bounds__(256, 2) void neuro_fused(
    const char*  __restrict__ xb,     // swizzled bf16 x tiles
    const float* __restrict__ ctx,    // [O_]
    const float* __restrict__ w,      // [O_, I_]
    const float* __restrict__ bias,   // [O_]
    const float* __restrict__ astro,  // [O_]
    const float* __restrict__ D,      // [O_, I_, SEG]
    float* __restrict__ out)          // [B_, O_]
{
    __shared__ __align__(16) char xs[4][XTILE];     // 32 KiB, 4-deep
    __shared__ __align__(16) char dls[4][4][DLS];   // [o_local][slot] 22 KiB

    const int tid  = threadIdx.x;
    const int wv   = tid >> 6;
    const int lane = tid & 63;
    const bool isP = (wv < 2);
    const int o0   = blockIdx.x * 4;
    const int col  = lane & 15;   // MFMA n-index
    const int g    = lane >> 4;   // k-group

    // ---- producer staging ---------------------------------------------------
    const int p = wv;   // 0,1 for producers
    auto stage_x = [&](int t) {
        const char* src = xb + (size_t)t * XTILE + p * 4096 + lane * 16;
        char* dst = &xs[t & 3][p * 4096];
#pragma unroll
        for (int c = 0; c < 4; ++c)
            GLDS16(src + c * 1024, dst + c * 1024);
    };
    auto stage_d = [&](int t) {
#pragma unroll
        for (int q = 0; q < 2; ++q) {
            const int ol = 2 * p + q;
            const char* srcD = (const char*)D + (size_t)(o0 + ol) * (I_ * SEG * 4)
                             + (size_t)t * DCH;
            char* dst = &dls[ol][t & 3][0];
            GLDS16(srcD + lane * 16, dst);
            GLDS4(srcD + 1024 + lane * 4, dst + 1024);
            const char* srcW = (const char*)w + (size_t)(o0 + ol) * (I_ * 4) + t * (BK * 4);
            if (lane < 32) GLDS4(srcW + lane * 4, dst + DCH);
        }
    };

    // ---- consumer state -----------------------------------------------------
    const int c_ = wv - 2;  // 0,1 for consumers
    f32x4 acc[2][8];
#pragma unroll
    for (int oo = 0; oo < 2; ++oo)
#pragma unroll
        for (int m = 0; m < 8; ++m) acc[oo][m] = (f32x4){0.f, 0.f, 0.f, 0.f};

    float am[2], bo[2];
    if (!isP) {
#pragma unroll
        for (int oo = 0; oo < 2; ++oo) {
            const int o = o0 + 2 * c_ + oo;
            float a = astro[o] * ctx[o];
            am[oo] = 1.0f / (1.0f + __expf(-a));
            bo[oo] = bias[o];
        }
    }

    const int fbase = (col < 10) ? col * 4 : DCH;
    const int fstr  = (col < 10) ? 40 : 4;
    const int sw    = ((col >> 1) & 3) << 4;

    auto compute = [&](int u) {
        const char* xbase = &xs[u & 3][0];
        bf16x8 af[8];
#pragma unroll
        for (int m = 0; m < 8; ++m)
            af[m] = *reinterpret_cast<const bf16x8*>(
                xbase + (m * 16 + col) * 64 + ((16 * g) ^ sw));
#pragma unroll
        for (int oo = 0; oo < 2; ++oo) {
            const char* fp = &dls[2 * c_ + oo][u & 3][0] + fbase + (8 * g) * fstr;
            float bv[8];
#pragma unroll
            for (int e = 0; e < 8; ++e)
                bv[e] = *reinterpret_cast<const float*>(fp + e * fstr);
            union { bf16x8 v; unsigned uu[4]; } bf;
#pragma unroll
            for (int e2 = 0; e2 < 4; ++e2)
                bf.uu[e2] = cvt2(bv[2 * e2], bv[2 * e2 + 1]);
#pragma unroll
            for (int m = 0; m < 8; ++m)
                acc[oo][m] = __builtin_amdgcn_mfma_f32_16x16x32_bf16(af[m], bf.v, acc[oo][m], 0, 0, 0);
        }
    };

    // ---- prologue: producers put 3 tiles in flight, tile 0 landed ----------
    if (isP) {
        stage_x(0); stage_d(0);
        stage_x(1); stage_d(1);
        stage_x(2); stage_d(2);
        WAITVM(20);   // tile 0 landed; tiles 1,2 (20 ops) in flight
    }

#pragma unroll 1
    for (int u = 0; u < NST; ++u) {
        BARRIER();    // tile u landed (producer waited last iter); slot (u+3)%4 free
        if (isP) {
            if (u + 3 < NST) { stage_x(u + 3); stage_d(u + 3); }
            if (u <= NST - 4)      { WAITVM(20); }  // tile u+1 landed by next barrier
            else if (u == NST - 3) { WAITVM(10); }
            else                   { WAITVM(0);  }
        } else {
            compute(u);
        }
    }

    // ---- epilogue (consumers only; no barriers after loop) -----------------
    if (!isP) {
#pragma unroll
        for (int oo = 0; oo < 2; ++oo) {
            const int o = o0 + 2 * c_ + oo;
#pragma unroll
            for (int m = 0; m < 8; ++m) {
#pragma unroll
                for (int r = 0; r < 4; ++r) {
                    float v = acc[oo][m][r];
                    float dend = (col < 10) ? fmaxf(v, 0.0f) : 0.0f;
#pragma unroll
                    for (int sh = 1; sh < 16; sh <<= 1)
                        dend += __shfl_xor(dend, sh, 64);
                    float lin = __shfl(v, (lane & 48) | 10, 64);
                    if (col == 0) {
                        int b = m * 16 + g * 4 + r;
                        out[(size_t)b * O_ + o] = dend + am[oo] * lin + bo[oo];
                    }
                }
            }
        }
    }
}

extern "C" void kernel_launch(void* const* d_in, const int* in_sizes, int n_in,
                              void* d_out, int out_size, void* d_ws, size_t ws_size,
                              hipStream_t stream) {
    const float* x     = (const float*)d_in[0];
    const float* ctx   = (const float*)d_in[1];
    // d_in[2] = prev_activation (unused by the reference output)
    const float* w     = (const float*)d_in[3];
    const float* bias  = (const float*)d_in[4];
    const float* astro = (const float*)d_in[5];
    const float* D     = (const float*)d_in[6];
    float* out = (float*)d_out;
    char* xb = (char*)d_ws;   // 512 KiB swizzled bf16 x

    xconv<<<dim3(128), dim3(256), 0, stream>>>(x, xb);
    neuro_fused<<<dim3(512), dim3(256), 0, stream>>>(xb, ctx, w, bias, astro, D, out);
}